// Round 5
// baseline (870.497 us; speedup 1.0000x reference)
//
#include <hip/hip_runtime.h>
#include <hip/hip_bf16.h>
#include <cmath>

#define HH 768
#define WW 768
#define HWSZ (768*768)

typedef __attribute__((ext_vector_type(8))) short bhalf8;   // 8 bf16 in 4 VGPRs
typedef __attribute__((ext_vector_type(4))) float f32x4;
typedef __attribute__((ext_vector_type(16))) float f32x16;

__device__ inline ushort f2bf(float f) {
  __hip_bfloat16 h = __float2bfloat16(f);
  return *reinterpret_cast<ushort*>(&h);
}
__device__ inline float bf2f(ushort u) {
  union { unsigned int i; float f; } v; v.i = ((unsigned int)u) << 16; return v.f;
}

// ---------------- weight transform: w1[m][c][ky][kx] fp32 -> wT[pos][m][c] bf16 (s-folded),
// ---------------- bb[m] = b1[m]*s[m] + t[m]
__global__ __launch_bounds__(256) void wxform_kernel(
    const float* __restrict__ w1, const float* __restrict__ b1,
    const float* __restrict__ s,  const float* __restrict__ t,
    ushort* __restrict__ wT, float* __restrict__ bb, int npos)
{
  int i = blockIdx.x * 256 + threadIdx.x;
  if (i < npos * 1024) {
    int pos = i >> 10, mc = i & 1023, m = mc >> 5, c = mc & 31;
    wT[i] = f2bf(w1[(m * 32 + c) * npos + pos] * s[m]);
  }
  if (i < 32) bb[i] = b1[i] * s[i] + t[i];
}

// ---------------- backbone: conv3x3 (3->32) + bias + relu, feats[b][y][x][c] bf16 ----------------
__global__ __launch_bounds__(256) void backbone_kernel(
    const float* __restrict__ x, const float* __restrict__ w,
    const float* __restrict__ bias, ushort* __restrict__ feats)
{
  int p = blockIdx.x * 256 + threadIdx.x;          // 0 .. 2*HW-1
  int bb  = p / HWSZ;
  int rem = p - bb * HWSZ;
  int y   = rem / WW;
  int xx  = rem - y * WW;
  const float* xb = x + (size_t)bb * 3 * HWSZ;

  float v[3][3][3];
  #pragma unroll
  for (int c = 0; c < 3; c++)
    #pragma unroll
    for (int dy = 0; dy < 3; dy++)
      #pragma unroll
      for (int dx = 0; dx < 3; dx++) {
        int yy = y + dy - 1, xq = xx + dx - 1;
        v[c][dy][dx] = (yy >= 0 && yy < HH && xq >= 0 && xq < WW)
                         ? xb[(size_t)c * HWSZ + yy * WW + xq] : 0.f;
      }

  union { ushort u[32]; uint4 q[4]; } pk;
  #pragma unroll
  for (int o = 0; o < 32; o++) {
    float acc = bias[o];
    #pragma unroll
    for (int c = 0; c < 3; c++)
      #pragma unroll
      for (int dy = 0; dy < 3; dy++)
        #pragma unroll
        for (int dx = 0; dx < 3; dx++)
          acc = fmaf(w[((o * 3 + c) * 3 + dy) * 3 + dx], v[c][dy][dx], acc);
    pk.u[o] = f2bf(fmaxf(acc, 0.f));
  }
  uint4* dst = (uint4*)(feats + ((size_t)bb * HWSZ + rem) * 32);
  #pragma unroll
  for (int i = 0; i < 4; i++) dst[i] = pk.q[i];
}

// ---------------- per-head epilogue: BN+relu -> bf16 mids in LDS -> 1x1 conv -> store ----------------
// mids layout: [pix][36] ushort (72B stride, 8B-aligned b64 writes, 2-way banks = free)
template <int COUT, bool DO_TANH>
__device__ inline void head_epilogue(
    const f32x16 acc[4], const float* __restrict__ bbh,
    const float* __restrict__ w2, const float* __restrict__ b2,
    float* __restrict__ out_base, ushort* mid,
    int wv, int q, int kg, int by, int bx, int bb)
{
  #pragma unroll
  for (int n = 0; n < 4; n++) {
    int pix = (wv * 4 + n) * 32 + q;
    #pragma unroll
    for (int rq = 0; rq < 4; rq++) {
      int m0 = 8 * rq + 4 * kg;
      ushort u[4];
      #pragma unroll
      for (int rr = 0; rr < 4; rr++)
        u[rr] = f2bf(fmaxf(acc[n][rq * 4 + rr] + bbh[m0 + rr], 0.f));
      uint2 pkv;
      pkv.x = (unsigned int)u[0] | ((unsigned int)u[1] << 16);
      pkv.y = (unsigned int)u[2] | ((unsigned int)u[3] << 16);
      *(uint2*)(mid + pix * 36 + m0) = pkv;
    }
  }
  __syncthreads();

  int t = threadIdx.x;
  #pragma unroll
  for (int rep = 0; rep < 2; rep++) {
    int pix = t + rep * 256;
    float mv[32];
    #pragma unroll
    for (int j = 0; j < 8; j++) {
      uint2 r = *(const uint2*)(mid + pix * 36 + j * 4);
      mv[j * 4 + 0] = bf2f((ushort)(r.x & 0xffff));
      mv[j * 4 + 1] = bf2f((ushort)(r.x >> 16));
      mv[j * 4 + 2] = bf2f((ushort)(r.y & 0xffff));
      mv[j * 4 + 3] = bf2f((ushort)(r.y >> 16));
    }
    int oy = by * 16 + (pix >> 5), ox = bx * 32 + (pix & 31);
    size_t opix = (size_t)oy * WW + ox;
    float* ob = out_base + (size_t)bb * COUT * HWSZ;
    #pragma unroll
    for (int oc = 0; oc < COUT; oc++) {
      float a2 = b2[oc];
      #pragma unroll
      for (int m = 0; m < 32; m++) a2 = fmaf(w2[oc * 32 + m], mv[m], a2);
      if (DO_TANH) a2 = tanhf(a2) * 3.0f;
      ob[(size_t)oc * HWSZ + opix] = a2;
    }
  }
  __syncthreads();   // before next head overwrites mid
}

// ---------------- two-head fused kernel, 16x32 output tile, N=4 n-groups/wave ----------------
template <bool GATE1, int COUT0, bool TANH0, int COUT1, bool TANH1>
__global__ __launch_bounds__(256, 2) void heads2_kernel(
    const ushort* __restrict__ feats,
    const ushort* __restrict__ wt0, const ushort* __restrict__ wt1,
    const float*  __restrict__ bbh0, const float* __restrict__ bbh1,
    const float* __restrict__ w20, const float* __restrict__ b20,
    const float* __restrict__ w21, const float* __restrict__ b21,
    float* __restrict__ out0, float* __restrict__ out1)
{
  constexpr int TR = 22, TC = 38, CPAD = 40;        // halo tile 22x38, 80B/pixel slot
  __shared__ __align__(16) ushort smem[TR * TC * CPAD];   // 66,880 B

  int bx = blockIdx.x % 24;                          // 24 tiles of 32 cols
  int by = (blockIdx.x / 24) % 48;                   // 48 tiles of 16 rows
  int bb = blockIdx.x / 1152;
  int x0 = bx * 32 - 3, y0 = by * 16 - 3;
  const ushort* fB = feats + (size_t)bb * HWSZ * 32;

  // ---- stage halo tile (all 32 ch per pixel, 64B contiguous) ----
  for (int p = threadIdx.x; p < TR * TC; p += 256) {
    int r = p / TC, cl = p - r * TC;
    int yy = y0 + r, xx = x0 + cl;
    uint4 q0 = {0,0,0,0}, q1 = {0,0,0,0}, q2 = {0,0,0,0}, q3 = {0,0,0,0};
    if (yy >= 0 && yy < HH && xx >= 0 && xx < WW) {
      const uint4* src = (const uint4*)(fB + ((size_t)yy * WW + xx) * 32);
      q0 = src[0]; q1 = src[1]; q2 = src[2]; q3 = src[3];
    }
    uint4* dst = (uint4*)(smem + (size_t)p * CPAD);
    dst[0] = q0; dst[1] = q1; dst[2] = q2; dst[3] = q3;
  }
  __syncthreads();

  const int l  = threadIdx.x & 63;
  const int wv = threadIdx.x >> 6;            // wave -> output rows wv*4 .. wv*4+3
  const int q  = l & 31;                      // A row (mid) / B col (pixel col)
  const int kg = l >> 5;                      // k-subgroup (8 ch)

  // per-lane B base (elements); all tap/n offsets are compile-time immediates
  const ushort* pb = smem + ((wv * 4) * TC + q) * CPAD + kg * 8;
  const int aoff = q * 32 + kg * 8;           // per-lane A offset within a tap

  f32x16 acc0[4] = {};
  f32x16 acc1[4] = {};

  #pragma unroll
  for (int ky = 0; ky < 7; ky++) {
    #pragma unroll
    for (int kx = 0; kx < 7; kx++) {
      const int tap = ky * 7 + kx;
      const bool act1 = !GATE1 || (ky >= 2 && ky <= 4 && kx >= 2 && kx <= 4);
      const int tap1 = GATE1 ? (ky - 2) * 3 + (kx - 2) : tap;

      bhalf8 a0[2], a1[2];
      #pragma unroll
      for (int kh = 0; kh < 2; kh++)
        a0[kh] = *(const bhalf8*)(wt0 + tap * 1024 + aoff + kh * 16);
      if (act1)
        #pragma unroll
        for (int kh = 0; kh < 2; kh++)
          a1[kh] = *(const bhalf8*)(wt1 + tap1 * 1024 + aoff + kh * 16);

      #pragma unroll
      for (int n = 0; n < 4; n++) {
        const ushort* bp = pb + ((n + ky) * TC + kx) * CPAD;
        bhalf8 b0 = *(const bhalf8*)(bp);
        bhalf8 b1 = *(const bhalf8*)(bp + 16);
        acc0[n] = __builtin_amdgcn_mfma_f32_32x32x16_bf16(a0[0], b0, acc0[n], 0, 0, 0);
        acc0[n] = __builtin_amdgcn_mfma_f32_32x32x16_bf16(a0[1], b1, acc0[n], 0, 0, 0);
        if (act1) {
          acc1[n] = __builtin_amdgcn_mfma_f32_32x32x16_bf16(a1[0], b0, acc1[n], 0, 0, 0);
          acc1[n] = __builtin_amdgcn_mfma_f32_32x32x16_bf16(a1[1], b1, acc1[n], 0, 0, 0);
        }
      }
    }
  }

  __syncthreads();                            // tile no longer needed
  ushort* mid = smem;                         // reuse: [512][36] ushort = 36,864 B

  head_epilogue<COUT0, TANH0>(acc0, bbh0, w20, b20, out0, mid, wv, q, kg, by, bx, bb);
  head_epilogue<COUT1, TANH1>(acc1, bbh1, w21, b21, out1, mid, wv, q, kg, by, bx, bb);
}

extern "C" void kernel_launch(void* const* d_in, const int* in_sizes, int n_in,
                              void* d_out, int out_size, void* d_ws, size_t ws_size,
                              hipStream_t stream) {
  const float* input = (const float*)d_in[0];
  const float* bb_w  = (const float*)d_in[1];
  const float* bb_b  = (const float*)d_in[2];

  ushort* feats = (ushort*)d_ws;                             // 2*HW*32 bf16 = 75.5 MB
  char* base = (char*)d_ws;
  const size_t FEATS_BYTES = (size_t)2 * HWSZ * 32 * 2;
  const size_t WT_STRIDE   = 49 * 1024 * 2;                  // bytes per head slot
  ushort* wT0 = (ushort*)(base + FEATS_BYTES);
  float*  bb0 = (float*)(base + FEATS_BYTES + 4 * WT_STRIDE);
  (void)out_size; (void)ws_size; (void)n_in; (void)in_sizes;

  float* out = (float*)d_out;
  // output chunks (elements): scores @0, loc @4HW, ref @8HW, four @12HW
  float* outS = out;
  float* outL = out + (size_t)4  * HWSZ;
  float* outR = out + (size_t)8  * HWSZ;
  float* outF = out + (size_t)12 * HWSZ;

  // weight transforms (head order: score, loc, four, ref)
  const int npos_h[4] = {9, 49, 49, 49};
  for (int h = 0; h < 4; h++) {
    const float* w1 = (const float*)d_in[3 + h * 6 + 0];
    const float* b1 = (const float*)d_in[3 + h * 6 + 1];
    const float* s  = (const float*)d_in[3 + h * 6 + 2];
    const float* t  = (const float*)d_in[3 + h * 6 + 3];
    ushort* wT = (ushort*)((char*)wT0 + h * WT_STRIDE);
    float*  bbv = bb0 + h * 32;
    int n = npos_h[h] * 1024;
    wxform_kernel<<<(n + 255) / 256, 256, 0, stream>>>(w1, b1, s, t, wT, bbv, npos_h[h]);
  }

  backbone_kernel<<<4608, 256, 0, stream>>>(input, bb_w, bb_b, feats);

  const ushort* wtS = (const ushort*)((char*)wT0 + 0 * WT_STRIDE);
  const ushort* wtL = (const ushort*)((char*)wT0 + 1 * WT_STRIDE);
  const ushort* wtF = (const ushort*)((char*)wT0 + 2 * WT_STRIDE);
  const ushort* wtR = (const ushort*)((char*)wT0 + 3 * WT_STRIDE);

  const int GRID = 2 * 48 * 24;                              // 2304

  // D1: loc (cout 2) + four (cout 20), both full 7x7
  heads2_kernel<false, 2, false, 20, false><<<GRID, 256, 0, stream>>>(
      feats, wtL, wtF, bb0 + 32, bb0 + 64,
      (const float*)d_in[13], (const float*)d_in[14],
      (const float*)d_in[19], (const float*)d_in[20],
      outL, outF);

  // D2: ref (cout 2, tanh) full 7x7 + score (cout 2) central-3x3-gated
  heads2_kernel<true, 2, true, 2, false><<<GRID, 256, 0, stream>>>(
      feats, wtR, wtS, bb0 + 96, bb0 + 0,
      (const float*)d_in[25], (const float*)d_in[26],
      (const float*)d_in[7],  (const float*)d_in[8],
      outR, outS);
}

// Round 6
// 501.436 us; speedup vs baseline: 1.7360x; 1.7360x over previous
//
#include <hip/hip_runtime.h>
#include <hip/hip_bf16.h>
#include <cmath>

#define HH 768
#define WW 768
#define HWSZ (768*768)

typedef __attribute__((ext_vector_type(8))) short bhalf8;   // 8 bf16 in 4 VGPRs
typedef __attribute__((ext_vector_type(4))) float f32x4;
typedef __attribute__((ext_vector_type(16))) float f32x16;

__device__ inline ushort f2bf(float f) {
  __hip_bfloat16 h = __float2bfloat16(f);
  return *reinterpret_cast<ushort*>(&h);
}

// ---------------- weight transform: w1[m][c][ky][kx] fp32 -> wT[pos][m][c] bf16 (s-folded),
// ---------------- bb[m] = b1[m]*s[m] + t[m]
__global__ __launch_bounds__(256) void wxform_kernel(
    const float* __restrict__ w1, const float* __restrict__ b1,
    const float* __restrict__ s,  const float* __restrict__ t,
    ushort* __restrict__ wT, float* __restrict__ bb, int npos)
{
  int i = blockIdx.x * 256 + threadIdx.x;
  if (i < npos * 1024) {
    int pos = i >> 10, mc = i & 1023, m = mc >> 5, c = mc & 31;
    wT[i] = f2bf(w1[(m * 32 + c) * npos + pos] * s[m]);
  }
  if (i < 32) bb[i] = b1[i] * s[i] + t[i];
}

// ---------------- backbone: conv3x3 (3->32) + bias + relu, feats[b][y][x][c] bf16 ----------------
__global__ __launch_bounds__(256) void backbone_kernel(
    const float* __restrict__ x, const float* __restrict__ w,
    const float* __restrict__ bias, ushort* __restrict__ feats)
{
  int p = blockIdx.x * 256 + threadIdx.x;          // 0 .. 2*HW-1
  int bb  = p / HWSZ;
  int rem = p - bb * HWSZ;
  int y   = rem / WW;
  int xx  = rem - y * WW;
  const float* xb = x + (size_t)bb * 3 * HWSZ;

  float v[3][3][3];
  #pragma unroll
  for (int c = 0; c < 3; c++)
    #pragma unroll
    for (int dy = 0; dy < 3; dy++)
      #pragma unroll
      for (int dx = 0; dx < 3; dx++) {
        int yy = y + dy - 1, xq = xx + dx - 1;
        v[c][dy][dx] = (yy >= 0 && yy < HH && xq >= 0 && xq < WW)
                         ? xb[(size_t)c * HWSZ + yy * WW + xq] : 0.f;
      }

  union { ushort u[32]; uint4 q[4]; } pk;
  #pragma unroll
  for (int o = 0; o < 32; o++) {
    float acc = bias[o];
    #pragma unroll
    for (int c = 0; c < 3; c++)
      #pragma unroll
      for (int dy = 0; dy < 3; dy++)
        #pragma unroll
        for (int dx = 0; dx < 3; dx++)
          acc = fmaf(w[((o * 3 + c) * 3 + dy) * 3 + dx], v[c][dy][dx], acc);
    pk.u[o] = f2bf(fmaxf(acc, 0.f));
  }
  uint4* dst = (uint4*)(feats + ((size_t)bb * HWSZ + rem) * 32);
  #pragma unroll
  for (int i = 0; i < 4; i++) dst[i] = pk.q[i];
}

// ---------------- per-head epilogue: BN+relu -> LDS -> 1x1 conv -> store ----------------
// mid: [256][36] f32
template <int COUT, bool DO_TANH>
__device__ inline void head_epilogue(
    const f32x16 acc[2], const float* __restrict__ bbh,
    const float* __restrict__ w2, const float* __restrict__ b2,
    float* __restrict__ out_base, float* mid,
    int wv, int qr, int qc, int kg, int by, int bx, int bb)
{
  #pragma unroll
  for (int n = 0; n < 2; n++) {
    int pix = (wv * 4 + 2 * n + qr) * 16 + qc;
    #pragma unroll
    for (int rg = 0; rg < 4; rg++) {
      int m0 = 8 * rg + 4 * kg;
      f32x4 v;
      #pragma unroll
      for (int j = 0; j < 4; j++)
        v[j] = fmaxf(acc[n][rg * 4 + j] + bbh[m0 + j], 0.f);
      *(f32x4*)(mid + pix * 36 + m0) = v;
    }
  }
  __syncthreads();

  int t = threadIdx.x;
  float mv[32];
  #pragma unroll
  for (int j2 = 0; j2 < 8; j2++)
    *(f32x4*)(mv + 4 * j2) = *(const f32x4*)(mid + t * 36 + 4 * j2);

  int oy = by * 16 + (t >> 4), ox = bx * 16 + (t & 15);
  size_t opix = (size_t)oy * WW + ox;
  float* ob = out_base + (size_t)bb * COUT * HWSZ;
  #pragma unroll
  for (int oc = 0; oc < COUT; oc++) {
    float a2 = b2[oc];
    #pragma unroll
    for (int m = 0; m < 32; m++) a2 = fmaf(w2[oc * 32 + m], mv[m], a2);
    if (DO_TANH) a2 = tanhf(a2) * 3.0f;
    ob[(size_t)oc * HWSZ + opix] = a2;
  }
  __syncthreads();   // before next head overwrites mid
}

// ---------------- heads3: loc + four + ref, all full 7x7, share every B-fragment ----------------
__global__ __launch_bounds__(256, 2) void heads3_kernel(
    const ushort* __restrict__ feats,
    const ushort* __restrict__ wtL, const ushort* __restrict__ wtF,
    const ushort* __restrict__ wtR,
    const float* __restrict__ bbL, const float* __restrict__ bbF,
    const float* __restrict__ bbR,
    const float* __restrict__ w2L, const float* __restrict__ b2L,
    const float* __restrict__ w2F, const float* __restrict__ b2F,
    const float* __restrict__ w2R, const float* __restrict__ b2R,
    float* __restrict__ outL, float* __restrict__ outF, float* __restrict__ outR)
{
  constexpr int TW = 22, CPAD = 40;                // 22x22 halo tile, 80B/pixel slot
  __shared__ __align__(16) char smem[TW * TW * CPAD * 2];   // 38720 B (>= 256*36*4)
  ushort* tile = (ushort*)smem;

  int bx = blockIdx.x % 48;
  int by = (blockIdx.x / 48) % 48;
  int bb = blockIdx.x / 2304;
  int x0 = bx * 16 - 3, y0 = by * 16 - 3;
  const ushort* fB = feats + (size_t)bb * HWSZ * 32;

  // ---- stage halo tile (all 32 ch per pixel) ----
  for (int p = threadIdx.x; p < TW * TW; p += 256) {
    int py = p / TW, pxx = p % TW;
    int yy = y0 + py, xx = x0 + pxx;
    uint4 q0 = {0,0,0,0}, q1 = {0,0,0,0}, q2 = {0,0,0,0}, q3 = {0,0,0,0};
    if (yy >= 0 && yy < HH && xx >= 0 && xx < WW) {
      const uint4* src = (const uint4*)(fB + ((size_t)yy * WW + xx) * 32);
      q0 = src[0]; q1 = src[1]; q2 = src[2]; q3 = src[3];
    }
    uint4* dst = (uint4*)(tile + (size_t)p * CPAD);
    dst[0] = q0; dst[1] = q1; dst[2] = q2; dst[3] = q3;
  }
  __syncthreads();

  int l  = threadIdx.x & 63;
  int wv = threadIdx.x >> 6;                 // wave 0..3 -> output rows wv*4..wv*4+3
  int q  = l & 31;                           // m row of A / pixel col of B
  int kg = l >> 5;                           // k-subgroup (8 elems)
  int qr = q >> 4, qc = q & 15;

  // per-lane B base: pixel (wv*4 + qr, qc), channels kg*8
  const ushort* pb = tile + ((wv * 4 + qr) * TW + qc) * CPAD + kg * 8;
  const int aoff = q * 32 + kg * 8;          // per-lane A offset within a tap

  f32x16 accL[2] = {};
  f32x16 accF[2] = {};
  f32x16 accR[2] = {};

  #pragma unroll
  for (int ky = 0; ky < 7; ky++) {
    #pragma unroll
    for (int kx = 0; kx < 7; kx++) {
      const int tap = ky * 7 + kx;

      bhalf8 aL[2], aF[2], aR[2];
      #pragma unroll
      for (int kh = 0; kh < 2; kh++) {
        aL[kh] = *(const bhalf8*)(wtL + tap * 1024 + aoff + kh * 16);
        aF[kh] = *(const bhalf8*)(wtF + tap * 1024 + aoff + kh * 16);
        aR[kh] = *(const bhalf8*)(wtR + tap * 1024 + aoff + kh * 16);
      }

      bhalf8 bfr[2][2];
      #pragma unroll
      for (int n = 0; n < 2; n++)
        #pragma unroll
        for (int kh = 0; kh < 2; kh++)
          bfr[n][kh] = *(const bhalf8*)(pb + (ky * TW + kx) * CPAD
                                           + n * 2 * TW * CPAD + kh * 16);

      #pragma unroll
      for (int n = 0; n < 2; n++)
        #pragma unroll
        for (int kh = 0; kh < 2; kh++) {
          accL[n] = __builtin_amdgcn_mfma_f32_32x32x16_bf16(aL[kh], bfr[n][kh], accL[n], 0, 0, 0);
          accF[n] = __builtin_amdgcn_mfma_f32_32x32x16_bf16(aF[kh], bfr[n][kh], accF[n], 0, 0, 0);
          accR[n] = __builtin_amdgcn_mfma_f32_32x32x16_bf16(aR[kh], bfr[n][kh], accR[n], 0, 0, 0);
        }
    }
  }

  __syncthreads();                            // tile no longer needed
  float* mid = (float*)smem;

  head_epilogue<2,  false>(accL, bbL, w2L, b2L, outL, mid, wv, qr, qc, kg, by, bx, bb);
  head_epilogue<20, false>(accF, bbF, w2F, b2F, outF, mid, wv, qr, qc, kg, by, bx, bb);
  head_epilogue<2,  true >(accR, bbR, w2R, b2R, outR, mid, wv, qr, qc, kg, by, bx, bb);
}

// ---------------- score: single head, 3x3, high occupancy ----------------
__global__ __launch_bounds__(256, 4) void score_kernel(
    const ushort* __restrict__ feats,
    const ushort* __restrict__ wtS, const float* __restrict__ bbS,
    const float* __restrict__ w2S, const float* __restrict__ b2S,
    float* __restrict__ outS)
{
  constexpr int TW = 18, CPAD = 40;                // 18x18 halo tile
  constexpr int SMEM_BYTES = 256 * 36 * 4;         // 36864 >= 18*18*80=25920
  __shared__ __align__(16) char smem[SMEM_BYTES];
  ushort* tile = (ushort*)smem;

  int bx = blockIdx.x % 48;
  int by = (blockIdx.x / 48) % 48;
  int bb = blockIdx.x / 2304;
  int x0 = bx * 16 - 1, y0 = by * 16 - 1;
  const ushort* fB = feats + (size_t)bb * HWSZ * 32;

  for (int p = threadIdx.x; p < TW * TW; p += 256) {
    int py = p / TW, pxx = p % TW;
    int yy = y0 + py, xx = x0 + pxx;
    uint4 q0 = {0,0,0,0}, q1 = {0,0,0,0}, q2 = {0,0,0,0}, q3 = {0,0,0,0};
    if (yy >= 0 && yy < HH && xx >= 0 && xx < WW) {
      const uint4* src = (const uint4*)(fB + ((size_t)yy * WW + xx) * 32);
      q0 = src[0]; q1 = src[1]; q2 = src[2]; q3 = src[3];
    }
    uint4* dst = (uint4*)(tile + (size_t)p * CPAD);
    dst[0] = q0; dst[1] = q1; dst[2] = q2; dst[3] = q3;
  }
  __syncthreads();

  int l  = threadIdx.x & 63;
  int wv = threadIdx.x >> 6;
  int q  = l & 31;
  int kg = l >> 5;
  int qr = q >> 4, qc = q & 15;

  const ushort* pb = tile + ((wv * 4 + qr) * TW + qc) * CPAD + kg * 8;
  const int aoff = q * 32 + kg * 8;

  f32x16 acc[2] = {};

  #pragma unroll
  for (int ky = 0; ky < 3; ky++) {
    #pragma unroll
    for (int kx = 0; kx < 3; kx++) {
      const int tap = ky * 3 + kx;
      bhalf8 a0[2];
      #pragma unroll
      for (int kh = 0; kh < 2; kh++)
        a0[kh] = *(const bhalf8*)(wtS + tap * 1024 + aoff + kh * 16);
      #pragma unroll
      for (int n = 0; n < 2; n++) {
        #pragma unroll
        for (int kh = 0; kh < 2; kh++) {
          bhalf8 bf = *(const bhalf8*)(pb + (ky * TW + kx) * CPAD
                                          + n * 2 * TW * CPAD + kh * 16);
          acc[n] = __builtin_amdgcn_mfma_f32_32x32x16_bf16(a0[kh], bf, acc[n], 0, 0, 0);
        }
      }
    }
  }

  __syncthreads();
  float* mid = (float*)smem;
  head_epilogue<2, false>(acc, bbS, w2S, b2S, outS, mid, wv, qr, qc, kg, by, bx, bb);
}

extern "C" void kernel_launch(void* const* d_in, const int* in_sizes, int n_in,
                              void* d_out, int out_size, void* d_ws, size_t ws_size,
                              hipStream_t stream) {
  const float* input = (const float*)d_in[0];
  const float* bb_w  = (const float*)d_in[1];
  const float* bb_b  = (const float*)d_in[2];

  ushort* feats = (ushort*)d_ws;                             // 2*HW*32 bf16 = 75.5 MB
  char* base = (char*)d_ws;
  const size_t FEATS_BYTES = (size_t)2 * HWSZ * 32 * 2;
  const size_t WT_STRIDE   = 49 * 1024 * 2;                  // bytes per head slot
  ushort* wT0 = (ushort*)(base + FEATS_BYTES);
  float*  bb0 = (float*)(base + FEATS_BYTES + 4 * WT_STRIDE);
  (void)out_size; (void)ws_size; (void)n_in; (void)in_sizes;

  float* out = (float*)d_out;
  // output chunks (elements): scores @0, loc @4HW, ref @8HW, four @12HW
  float* outS = out;
  float* outL = out + (size_t)4  * HWSZ;
  float* outR = out + (size_t)8  * HWSZ;
  float* outF = out + (size_t)12 * HWSZ;

  // weight transforms (head order: score, loc, four, ref)
  const int npos_h[4] = {9, 49, 49, 49};
  for (int h = 0; h < 4; h++) {
    const float* w1 = (const float*)d_in[3 + h * 6 + 0];
    const float* b1 = (const float*)d_in[3 + h * 6 + 1];
    const float* s  = (const float*)d_in[3 + h * 6 + 2];
    const float* t  = (const float*)d_in[3 + h * 6 + 3];
    ushort* wT = (ushort*)((char*)wT0 + h * WT_STRIDE);
    float*  bbv = bb0 + h * 32;
    int n = npos_h[h] * 1024;
    wxform_kernel<<<(n + 255) / 256, 256, 0, stream>>>(w1, b1, s, t, wT, bbv, npos_h[h]);
  }

  backbone_kernel<<<4608, 256, 0, stream>>>(input, bb_w, bb_b, feats);

  const ushort* wtS = (const ushort*)((char*)wT0 + 0 * WT_STRIDE);
  const ushort* wtL = (const ushort*)((char*)wT0 + 1 * WT_STRIDE);
  const ushort* wtF = (const ushort*)((char*)wT0 + 2 * WT_STRIDE);
  const ushort* wtR = (const ushort*)((char*)wT0 + 3 * WT_STRIDE);

  const int GRID = 2 * 48 * 48;                              // 4608

  heads3_kernel<<<GRID, 256, 0, stream>>>(
      feats, wtL, wtF, wtR,
      bb0 + 32, bb0 + 64, bb0 + 96,
      (const float*)d_in[13], (const float*)d_in[14],
      (const float*)d_in[19], (const float*)d_in[20],
      (const float*)d_in[25], (const float*)d_in[26],
      outL, outF, outR);

  score_kernel<<<GRID, 256, 0, stream>>>(
      feats, wtS, bb0 + 0,
      (const float*)d_in[7], (const float*)d_in[8], outS);
}

// Round 7
// 469.034 us; speedup vs baseline: 1.8559x; 1.0691x over previous
//
#include <hip/hip_runtime.h>
#include <hip/hip_bf16.h>
#include <cmath>

#define HH 768
#define WW 768
#define HWSZ (768*768)

typedef __attribute__((ext_vector_type(8))) short bhalf8;   // 8 bf16 in 4 VGPRs
typedef __attribute__((ext_vector_type(4))) float f32x4;
typedef __attribute__((ext_vector_type(16))) float f32x16;

__device__ inline ushort f2bf(float f) {
  __hip_bfloat16 h = __float2bfloat16(f);
  return *reinterpret_cast<ushort*>(&h);
}

// ---------------- weight transform: w1[m][c][ky][kx] fp32 -> wT[pos][m][c] bf16 (s-folded),
// ---------------- bb[m] = b1[m]*s[m] + t[m]
__global__ __launch_bounds__(256) void wxform_kernel(
    const float* __restrict__ w1, const float* __restrict__ b1,
    const float* __restrict__ s,  const float* __restrict__ t,
    ushort* __restrict__ wT, float* __restrict__ bb, int npos)
{
  int i = blockIdx.x * 256 + threadIdx.x;
  if (i < npos * 1024) {
    int pos = i >> 10, mc = i & 1023, m = mc >> 5, c = mc & 31;
    wT[i] = f2bf(w1[(m * 32 + c) * npos + pos] * s[m]);
  }
  if (i < 32) bb[i] = b1[i] * s[i] + t[i];
}

// ---------------- backbone: conv3x3 (3->32) + bias + relu, feats[b][y][x][c] bf16 ----------------
__global__ __launch_bounds__(256) void backbone_kernel(
    const float* __restrict__ x, const float* __restrict__ w,
    const float* __restrict__ bias, ushort* __restrict__ feats)
{
  int p = blockIdx.x * 256 + threadIdx.x;          // 0 .. 2*HW-1
  int bb  = p / HWSZ;
  int rem = p - bb * HWSZ;
  int y   = rem / WW;
  int xx  = rem - y * WW;
  const float* xb = x + (size_t)bb * 3 * HWSZ;

  float v[3][3][3];
  #pragma unroll
  for (int c = 0; c < 3; c++)
    #pragma unroll
    for (int dy = 0; dy < 3; dy++)
      #pragma unroll
      for (int dx = 0; dx < 3; dx++) {
        int yy = y + dy - 1, xq = xx + dx - 1;
        v[c][dy][dx] = (yy >= 0 && yy < HH && xq >= 0 && xq < WW)
                         ? xb[(size_t)c * HWSZ + yy * WW + xq] : 0.f;
      }

  union { ushort u[32]; uint4 q[4]; } pk;
  #pragma unroll
  for (int o = 0; o < 32; o++) {
    float acc = bias[o];
    #pragma unroll
    for (int c = 0; c < 3; c++)
      #pragma unroll
      for (int dy = 0; dy < 3; dy++)
        #pragma unroll
        for (int dx = 0; dx < 3; dx++)
          acc = fmaf(w[((o * 3 + c) * 3 + dy) * 3 + dx], v[c][dy][dx], acc);
    pk.u[o] = f2bf(fmaxf(acc, 0.f));
  }
  uint4* dst = (uint4*)(feats + ((size_t)bb * HWSZ + rem) * 32);
  #pragma unroll
  for (int i = 0; i < 4; i++) dst[i] = pk.q[i];
}

// ---------------- per-head epilogue: BN+relu -> LDS -> 1x1 conv -> store ----------------
// mid: [256][36] f32
template <int COUT, bool DO_TANH>
__device__ inline void head_epilogue(
    const f32x16 acc[2], const float* __restrict__ bbh,
    const float* __restrict__ w2, const float* __restrict__ b2,
    float* __restrict__ out_base, float* mid,
    int wv, int qr, int qc, int kg, int by, int bx, int bb)
{
  #pragma unroll
  for (int n = 0; n < 2; n++) {
    int pix = (wv * 4 + 2 * n + qr) * 16 + qc;
    #pragma unroll
    for (int rg = 0; rg < 4; rg++) {
      int m0 = 8 * rg + 4 * kg;
      f32x4 v;
      #pragma unroll
      for (int j = 0; j < 4; j++)
        v[j] = fmaxf(acc[n][rg * 4 + j] + bbh[m0 + j], 0.f);
      *(f32x4*)(mid + pix * 36 + m0) = v;
    }
  }
  __syncthreads();

  int t = threadIdx.x;
  float mv[32];
  #pragma unroll
  for (int j2 = 0; j2 < 8; j2++)
    *(f32x4*)(mv + 4 * j2) = *(const f32x4*)(mid + t * 36 + 4 * j2);

  int oy = by * 16 + (t >> 4), ox = bx * 16 + (t & 15);
  size_t opix = (size_t)oy * WW + ox;
  float* ob = out_base + (size_t)bb * COUT * HWSZ;
  #pragma unroll
  for (int oc = 0; oc < COUT; oc++) {
    float a2 = b2[oc];
    #pragma unroll
    for (int m = 0; m < 32; m++) a2 = fmaf(w2[oc * 32 + m], mv[m], a2);
    if (DO_TANH) a2 = tanhf(a2) * 3.0f;
    ob[(size_t)oc * HWSZ + opix] = a2;
  }
  __syncthreads();   // before next head overwrites mid
}

// ---------------- heads3: loc + four + ref, all full 7x7, share every B-fragment ----------------
// ky loop is DYNAMIC (#pragma unroll 1): limits the scheduler window to one kernel row
// (7 taps, 42 A-loads) so the unified register file is not blown -> no scratch spill.
__global__ __launch_bounds__(256, 2) void heads3_kernel(
    const ushort* __restrict__ feats,
    const ushort* __restrict__ wtL, const ushort* __restrict__ wtF,
    const ushort* __restrict__ wtR,
    const float* __restrict__ bbL, const float* __restrict__ bbF,
    const float* __restrict__ bbR,
    const float* __restrict__ w2L, const float* __restrict__ b2L,
    const float* __restrict__ w2F, const float* __restrict__ b2F,
    const float* __restrict__ w2R, const float* __restrict__ b2R,
    float* __restrict__ outL, float* __restrict__ outF, float* __restrict__ outR)
{
  constexpr int TW = 22, CPAD = 40;                // 22x22 halo tile, 80B/pixel slot
  __shared__ __align__(16) char smem[TW * TW * CPAD * 2];   // 38720 B (>= 256*36*4)
  ushort* tile = (ushort*)smem;

  int bx = blockIdx.x % 48;
  int by = (blockIdx.x / 48) % 48;
  int bb = blockIdx.x / 2304;
  int x0 = bx * 16 - 3, y0 = by * 16 - 3;
  const ushort* fB = feats + (size_t)bb * HWSZ * 32;

  // ---- stage halo tile (all 32 ch per pixel) ----
  for (int p = threadIdx.x; p < TW * TW; p += 256) {
    int py = p / TW, pxx = p % TW;
    int yy = y0 + py, xx = x0 + pxx;
    uint4 q0 = {0,0,0,0}, q1 = {0,0,0,0}, q2 = {0,0,0,0}, q3 = {0,0,0,0};
    if (yy >= 0 && yy < HH && xx >= 0 && xx < WW) {
      const uint4* src = (const uint4*)(fB + ((size_t)yy * WW + xx) * 32);
      q0 = src[0]; q1 = src[1]; q2 = src[2]; q3 = src[3];
    }
    uint4* dst = (uint4*)(tile + (size_t)p * CPAD);
    dst[0] = q0; dst[1] = q1; dst[2] = q2; dst[3] = q3;
  }
  __syncthreads();

  int l  = threadIdx.x & 63;
  int wv = threadIdx.x >> 6;                 // wave 0..3 -> output rows wv*4..wv*4+3
  int q  = l & 31;                           // m row of A / pixel col of B
  int kg = l >> 5;                           // k-subgroup (8 elems)
  int qr = q >> 4, qc = q & 15;

  // per-lane B base: pixel (wv*4 + qr, qc), channels kg*8
  const ushort* pb = tile + ((wv * 4 + qr) * TW + qc) * CPAD + kg * 8;
  const int aoff = q * 32 + kg * 8;          // per-lane A offset within a tap

  f32x16 accL[2] = {};
  f32x16 accF[2] = {};
  f32x16 accR[2] = {};

  #pragma unroll 1
  for (int ky = 0; ky < 7; ky++) {
    // per-row bases; all inner offsets are compile-time immediates
    const ushort* pbrow = pb + ky * TW * CPAD;
    const ushort* aL = wtL + ky * 7 * 1024 + aoff;
    const ushort* aF = wtF + ky * 7 * 1024 + aoff;
    const ushort* aR = wtR + ky * 7 * 1024 + aoff;

    #pragma unroll
    for (int kx = 0; kx < 7; kx++) {
      bhalf8 fL[2], fF[2], fR[2];
      #pragma unroll
      for (int kh = 0; kh < 2; kh++) {
        fL[kh] = *(const bhalf8*)(aL + kx * 1024 + kh * 16);
        fF[kh] = *(const bhalf8*)(aF + kx * 1024 + kh * 16);
        fR[kh] = *(const bhalf8*)(aR + kx * 1024 + kh * 16);
      }

      bhalf8 bfr[2][2];
      #pragma unroll
      for (int n = 0; n < 2; n++)
        #pragma unroll
        for (int kh = 0; kh < 2; kh++)
          bfr[n][kh] = *(const bhalf8*)(pbrow + kx * CPAD
                                           + n * 2 * TW * CPAD + kh * 16);

      #pragma unroll
      for (int n = 0; n < 2; n++)
        #pragma unroll
        for (int kh = 0; kh < 2; kh++) {
          accL[n] = __builtin_amdgcn_mfma_f32_32x32x16_bf16(fL[kh], bfr[n][kh], accL[n], 0, 0, 0);
          accF[n] = __builtin_amdgcn_mfma_f32_32x32x16_bf16(fF[kh], bfr[n][kh], accF[n], 0, 0, 0);
          accR[n] = __builtin_amdgcn_mfma_f32_32x32x16_bf16(fR[kh], bfr[n][kh], accR[n], 0, 0, 0);
        }
    }
  }

  __syncthreads();                            // tile no longer needed
  float* mid = (float*)smem;

  head_epilogue<2,  false>(accL, bbL, w2L, b2L, outL, mid, wv, qr, qc, kg, by, bx, bb);
  head_epilogue<20, false>(accF, bbF, w2F, b2F, outF, mid, wv, qr, qc, kg, by, bx, bb);
  head_epilogue<2,  true >(accR, bbR, w2R, b2R, outR, mid, wv, qr, qc, kg, by, bx, bb);
}

// ---------------- score: single head, 3x3, high occupancy ----------------
__global__ __launch_bounds__(256, 4) void score_kernel(
    const ushort* __restrict__ feats,
    const ushort* __restrict__ wtS, const float* __restrict__ bbS,
    const float* __restrict__ w2S, const float* __restrict__ b2S,
    float* __restrict__ outS)
{
  constexpr int TW = 18, CPAD = 40;                // 18x18 halo tile
  constexpr int SMEM_BYTES = 256 * 36 * 4;         // 36864 >= 18*18*80=25920
  __shared__ __align__(16) char smem[SMEM_BYTES];
  ushort* tile = (ushort*)smem;

  int bx = blockIdx.x % 48;
  int by = (blockIdx.x / 48) % 48;
  int bb = blockIdx.x / 2304;
  int x0 = bx * 16 - 1, y0 = by * 16 - 1;
  const ushort* fB = feats + (size_t)bb * HWSZ * 32;

  for (int p = threadIdx.x; p < TW * TW; p += 256) {
    int py = p / TW, pxx = p % TW;
    int yy = y0 + py, xx = x0 + pxx;
    uint4 q0 = {0,0,0,0}, q1 = {0,0,0,0}, q2 = {0,0,0,0}, q3 = {0,0,0,0};
    if (yy >= 0 && yy < HH && xx >= 0 && xx < WW) {
      const uint4* src = (const uint4*)(fB + ((size_t)yy * WW + xx) * 32);
      q0 = src[0]; q1 = src[1]; q2 = src[2]; q3 = src[3];
    }
    uint4* dst = (uint4*)(tile + (size_t)p * CPAD);
    dst[0] = q0; dst[1] = q1; dst[2] = q2; dst[3] = q3;
  }
  __syncthreads();

  int l  = threadIdx.x & 63;
  int wv = threadIdx.x >> 6;
  int q  = l & 31;
  int kg = l >> 5;
  int qr = q >> 4, qc = q & 15;

  const ushort* pb = tile + ((wv * 4 + qr) * TW + qc) * CPAD + kg * 8;
  const int aoff = q * 32 + kg * 8;

  f32x16 acc[2] = {};

  #pragma unroll
  for (int ky = 0; ky < 3; ky++) {
    #pragma unroll
    for (int kx = 0; kx < 3; kx++) {
      const int tap = ky * 3 + kx;
      bhalf8 a0[2];
      #pragma unroll
      for (int kh = 0; kh < 2; kh++)
        a0[kh] = *(const bhalf8*)(wtS + tap * 1024 + aoff + kh * 16);
      #pragma unroll
      for (int n = 0; n < 2; n++) {
        #pragma unroll
        for (int kh = 0; kh < 2; kh++) {
          bhalf8 bf = *(const bhalf8*)(pb + (ky * TW + kx) * CPAD
                                          + n * 2 * TW * CPAD + kh * 16);
          acc[n] = __builtin_amdgcn_mfma_f32_32x32x16_bf16(a0[kh], bf, acc[n], 0, 0, 0);
        }
      }
    }
  }

  __syncthreads();
  float* mid = (float*)smem;
  head_epilogue<2, false>(acc, bbS, w2S, b2S, outS, mid, wv, qr, qc, kg, by, bx, bb);
}

extern "C" void kernel_launch(void* const* d_in, const int* in_sizes, int n_in,
                              void* d_out, int out_size, void* d_ws, size_t ws_size,
                              hipStream_t stream) {
  const float* input = (const float*)d_in[0];
  const float* bb_w  = (const float*)d_in[1];
  const float* bb_b  = (const float*)d_in[2];

  ushort* feats = (ushort*)d_ws;                             // 2*HW*32 bf16 = 75.5 MB
  char* base = (char*)d_ws;
  const size_t FEATS_BYTES = (size_t)2 * HWSZ * 32 * 2;
  const size_t WT_STRIDE   = 49 * 1024 * 2;                  // bytes per head slot
  ushort* wT0 = (ushort*)(base + FEATS_BYTES);
  float*  bb0 = (float*)(base + FEATS_BYTES + 4 * WT_STRIDE);
  (void)out_size; (void)ws_size; (void)n_in; (void)in_sizes;

  float* out = (float*)d_out;
  // output chunks (elements): scores @0, loc @4HW, ref @8HW, four @12HW
  float* outS = out;
  float* outL = out + (size_t)4  * HWSZ;
  float* outR = out + (size_t)8  * HWSZ;
  float* outF = out + (size_t)12 * HWSZ;

  // weight transforms (head order: score, loc, four, ref)
  const int npos_h[4] = {9, 49, 49, 49};
  for (int h = 0; h < 4; h++) {
    const float* w1 = (const float*)d_in[3 + h * 6 + 0];
    const float* b1 = (const float*)d_in[3 + h * 6 + 1];
    const float* s  = (const float*)d_in[3 + h * 6 + 2];
    const float* t  = (const float*)d_in[3 + h * 6 + 3];
    ushort* wT = (ushort*)((char*)wT0 + h * WT_STRIDE);
    float*  bbv = bb0 + h * 32;
    int n = npos_h[h] * 1024;
    wxform_kernel<<<(n + 255) / 256, 256, 0, stream>>>(w1, b1, s, t, wT, bbv, npos_h[h]);
  }

  backbone_kernel<<<4608, 256, 0, stream>>>(input, bb_w, bb_b, feats);

  const ushort* wtS = (const ushort*)((char*)wT0 + 0 * WT_STRIDE);
  const ushort* wtL = (const ushort*)((char*)wT0 + 1 * WT_STRIDE);
  const ushort* wtF = (const ushort*)((char*)wT0 + 2 * WT_STRIDE);
  const ushort* wtR = (const ushort*)((char*)wT0 + 3 * WT_STRIDE);

  const int GRID = 2 * 48 * 48;                              // 4608

  heads3_kernel<<<GRID, 256, 0, stream>>>(
      feats, wtL, wtF, wtR,
      bb0 + 32, bb0 + 64, bb0 + 96,
      (const float*)d_in[13], (const float*)d_in[14],
      (const float*)d_in[19], (const float*)d_in[20],
      (const float*)d_in[25], (const float*)d_in[26],
      outL, outF, outR);

  score_kernel<<<GRID, 256, 0, stream>>>(
      feats, wtS, bb0 + 0,
      (const float*)d_in[7], (const float*)d_in[8], outS);
}

// Round 8
// 450.152 us; speedup vs baseline: 1.9338x; 1.0419x over previous
//
#include <hip/hip_runtime.h>
#include <hip/hip_bf16.h>
#include <cmath>

#define HH 768
#define WW 768
#define HWSZ (768*768)

typedef __attribute__((ext_vector_type(8))) short bhalf8;   // 8 bf16 in 4 VGPRs
typedef __attribute__((ext_vector_type(4))) float f32x4;
typedef __attribute__((ext_vector_type(16))) float f32x16;

__device__ inline ushort f2bf(float f) {
  __hip_bfloat16 h = __float2bfloat16(f);
  return *reinterpret_cast<ushort*>(&h);
}

// ---------------- merged weight transform for all 4 heads ----------------
// grid.y = head index; w1[m][c][ky][kx] fp32 -> wT[pos][m][c] bf16 (s-folded); bb = b1*s + t
__global__ __launch_bounds__(256) void wxform_all_kernel(
    const float* __restrict__ w1S, const float* __restrict__ b1S,
    const float* __restrict__ sS,  const float* __restrict__ tS,
    const float* __restrict__ w1L, const float* __restrict__ b1L,
    const float* __restrict__ sL,  const float* __restrict__ tL,
    const float* __restrict__ w1F, const float* __restrict__ b1F,
    const float* __restrict__ sF,  const float* __restrict__ tF,
    const float* __restrict__ w1R, const float* __restrict__ b1R,
    const float* __restrict__ sR,  const float* __restrict__ tR,
    ushort* __restrict__ wT0, float* __restrict__ bb0, size_t wt_stride_elems)
{
  int h = blockIdx.y;
  const float *w1, *b1, *s, *t;
  int npos;
  if (h == 0)      { w1 = w1S; b1 = b1S; s = sS; t = tS; npos = 9;  }
  else if (h == 1) { w1 = w1L; b1 = b1L; s = sL; t = tL; npos = 49; }
  else if (h == 2) { w1 = w1F; b1 = b1F; s = sF; t = tF; npos = 49; }
  else             { w1 = w1R; b1 = b1R; s = sR; t = tR; npos = 49; }

  ushort* wT = wT0 + (size_t)h * wt_stride_elems;
  float*  bb = bb0 + h * 32;

  int i = blockIdx.x * 256 + threadIdx.x;
  if (i < npos * 1024) {
    int pos = i >> 10, mc = i & 1023, m = mc >> 5, c = mc & 31;
    wT[i] = f2bf(w1[(m * 32 + c) * npos + pos] * s[m]);
  }
  if (blockIdx.x == 0 && i < 32) bb[i] = b1[i] * s[i] + t[i];
}

// ---------------- backbone: conv3x3 (3->32) + bias + relu, feats[b][y][x][c] bf16 ----------------
__global__ __launch_bounds__(256) void backbone_kernel(
    const float* __restrict__ x, const float* __restrict__ w,
    const float* __restrict__ bias, ushort* __restrict__ feats)
{
  int p = blockIdx.x * 256 + threadIdx.x;          // 0 .. 2*HW-1
  int bb  = p / HWSZ;
  int rem = p - bb * HWSZ;
  int y   = rem / WW;
  int xx  = rem - y * WW;
  const float* xb = x + (size_t)bb * 3 * HWSZ;

  float v[3][3][3];
  #pragma unroll
  for (int c = 0; c < 3; c++)
    #pragma unroll
    for (int dy = 0; dy < 3; dy++)
      #pragma unroll
      for (int dx = 0; dx < 3; dx++) {
        int yy = y + dy - 1, xq = xx + dx - 1;
        v[c][dy][dx] = (yy >= 0 && yy < HH && xq >= 0 && xq < WW)
                         ? xb[(size_t)c * HWSZ + yy * WW + xq] : 0.f;
      }

  union { ushort u[32]; uint4 q[4]; } pk;
  #pragma unroll
  for (int o = 0; o < 32; o++) {
    float acc = bias[o];
    #pragma unroll
    for (int c = 0; c < 3; c++)
      #pragma unroll
      for (int dy = 0; dy < 3; dy++)
        #pragma unroll
        for (int dx = 0; dx < 3; dx++)
          acc = fmaf(w[((o * 3 + c) * 3 + dy) * 3 + dx], v[c][dy][dx], acc);
    pk.u[o] = f2bf(fmaxf(acc, 0.f));
  }
  uint4* dst = (uint4*)(feats + ((size_t)bb * HWSZ + rem) * 32);
  #pragma unroll
  for (int i = 0; i < 4; i++) dst[i] = pk.q[i];
}

// ---------------- per-head epilogue: BN+relu -> LDS -> 1x1 conv -> store ----------------
// mid: [256][36] f32
template <int COUT, bool DO_TANH>
__device__ inline void head_epilogue(
    const f32x16 acc[2], const float* __restrict__ bbh,
    const float* __restrict__ w2, const float* __restrict__ b2,
    float* __restrict__ out_base, float* mid,
    int wv, int qr, int qc, int kg, int by, int bx, int bb)
{
  #pragma unroll
  for (int n = 0; n < 2; n++) {
    int pix = (wv * 4 + 2 * n + qr) * 16 + qc;
    #pragma unroll
    for (int rg = 0; rg < 4; rg++) {
      int m0 = 8 * rg + 4 * kg;
      f32x4 v;
      #pragma unroll
      for (int j = 0; j < 4; j++)
        v[j] = fmaxf(acc[n][rg * 4 + j] + bbh[m0 + j], 0.f);
      *(f32x4*)(mid + pix * 36 + m0) = v;
    }
  }
  __syncthreads();

  int t = threadIdx.x;
  float mv[32];
  #pragma unroll
  for (int j2 = 0; j2 < 8; j2++)
    *(f32x4*)(mv + 4 * j2) = *(const f32x4*)(mid + t * 36 + 4 * j2);

  int oy = by * 16 + (t >> 4), ox = bx * 16 + (t & 15);
  size_t opix = (size_t)oy * WW + ox;
  float* ob = out_base + (size_t)bb * COUT * HWSZ;
  #pragma unroll
  for (int oc = 0; oc < COUT; oc++) {
    float a2 = b2[oc];
    #pragma unroll
    for (int m = 0; m < 32; m++) a2 = fmaf(w2[oc * 32 + m], mv[m], a2);
    if (DO_TANH) a2 = tanhf(a2) * 3.0f;
    ob[(size_t)oc * HWSZ + opix] = a2;
  }
  __syncthreads();   // before next head overwrites mid
}

// ---------------- two-head fused kernel: dynamic ky (anti-spill), 3 waves/SIMD ----------------
template <bool GATE1, int COUT0, bool TANH0, int COUT1, bool TANH1>
__global__ __launch_bounds__(256, 3) void heads2_kernel(
    const ushort* __restrict__ feats,
    const ushort* __restrict__ wt0, const ushort* __restrict__ wt1,
    const float*  __restrict__ bbh0, const float* __restrict__ bbh1,
    const float* __restrict__ w20, const float* __restrict__ b20,
    const float* __restrict__ w21, const float* __restrict__ b21,
    float* __restrict__ out0, float* __restrict__ out1)
{
  constexpr int TW = 22, CPAD = 40;                // 22x22 halo tile, 80B/pixel slot
  __shared__ __align__(16) char smem[TW * TW * CPAD * 2];   // 38720 B (>= 256*36*4)
  ushort* tile = (ushort*)smem;

  int bx = blockIdx.x % 48;
  int by = (blockIdx.x / 48) % 48;
  int bb = blockIdx.x / 2304;
  int x0 = bx * 16 - 3, y0 = by * 16 - 3;
  const ushort* fB = feats + (size_t)bb * HWSZ * 32;

  // ---- stage halo tile (all 32 ch per pixel) ----
  for (int p = threadIdx.x; p < TW * TW; p += 256) {
    int py = p / TW, pxx = p % TW;
    int yy = y0 + py, xx = x0 + pxx;
    uint4 q0 = {0,0,0,0}, q1 = {0,0,0,0}, q2 = {0,0,0,0}, q3 = {0,0,0,0};
    if (yy >= 0 && yy < HH && xx >= 0 && xx < WW) {
      const uint4* src = (const uint4*)(fB + ((size_t)yy * WW + xx) * 32);
      q0 = src[0]; q1 = src[1]; q2 = src[2]; q3 = src[3];
    }
    uint4* dst = (uint4*)(tile + (size_t)p * CPAD);
    dst[0] = q0; dst[1] = q1; dst[2] = q2; dst[3] = q3;
  }
  __syncthreads();

  int l  = threadIdx.x & 63;
  int wv = threadIdx.x >> 6;                 // wave 0..3 -> output rows wv*4..wv*4+3
  int q  = l & 31;                           // m row of A / pixel col of B
  int kg = l >> 5;                           // k-subgroup (8 elems)
  int qr = q >> 4, qc = q & 15;

  // per-lane B base: pixel (wv*4 + qr, qc), channels kg*8
  const ushort* pb = tile + ((wv * 4 + qr) * TW + qc) * CPAD + kg * 8;
  const int aoff = q * 32 + kg * 8;          // per-lane A offset within a tap

  f32x16 acc0[2] = {};
  f32x16 acc1[2] = {};

  #pragma unroll 1
  for (int ky = 0; ky < 7; ky++) {
    const bool act1row = !GATE1 || (ky >= 2 && ky <= 4);
    const ushort* pbrow = pb + ky * TW * CPAD;
    const ushort* a0r = wt0 + ky * 7 * 1024 + aoff;
    // for GATE1 (3x3 head): tap1 = (ky-2)*3 + (kx-2) -> base + kx*1024
    const ushort* a1r = GATE1 ? (wt1 + ((ky - 2) * 3 - 2) * 1024 + aoff)
                              : (wt1 + ky * 7 * 1024 + aoff);

    #pragma unroll
    for (int kx = 0; kx < 7; kx++) {
      const bool act1 = act1row && (!GATE1 || (kx >= 2 && kx <= 4));

      bhalf8 f0[2], f1[2];
      #pragma unroll
      for (int kh = 0; kh < 2; kh++)
        f0[kh] = *(const bhalf8*)(a0r + kx * 1024 + kh * 16);
      if (act1)
        #pragma unroll
        for (int kh = 0; kh < 2; kh++)
          f1[kh] = *(const bhalf8*)(a1r + kx * 1024 + kh * 16);

      bhalf8 bfr[2][2];
      #pragma unroll
      for (int n = 0; n < 2; n++)
        #pragma unroll
        for (int kh = 0; kh < 2; kh++)
          bfr[n][kh] = *(const bhalf8*)(pbrow + kx * CPAD
                                           + n * 2 * TW * CPAD + kh * 16);

      #pragma unroll
      for (int n = 0; n < 2; n++)
        #pragma unroll
        for (int kh = 0; kh < 2; kh++) {
          acc0[n] = __builtin_amdgcn_mfma_f32_32x32x16_bf16(f0[kh], bfr[n][kh], acc0[n], 0, 0, 0);
          if (act1)
            acc1[n] = __builtin_amdgcn_mfma_f32_32x32x16_bf16(f1[kh], bfr[n][kh], acc1[n], 0, 0, 0);
        }
    }
  }

  __syncthreads();                            // tile no longer needed
  float* mid = (float*)smem;

  head_epilogue<COUT0, TANH0>(acc0, bbh0, w20, b20, out0, mid, wv, qr, qc, kg, by, bx, bb);
  head_epilogue<COUT1, TANH1>(acc1, bbh1, w21, b21, out1, mid, wv, qr, qc, kg, by, bx, bb);
}

extern "C" void kernel_launch(void* const* d_in, const int* in_sizes, int n_in,
                              void* d_out, int out_size, void* d_ws, size_t ws_size,
                              hipStream_t stream) {
  const float* input = (const float*)d_in[0];
  const float* bb_w  = (const float*)d_in[1];
  const float* bb_b  = (const float*)d_in[2];

  ushort* feats = (ushort*)d_ws;                             // 2*HW*32 bf16 = 75.5 MB
  char* base = (char*)d_ws;
  const size_t FEATS_BYTES = (size_t)2 * HWSZ * 32 * 2;
  const size_t WT_STRIDE_E = 49 * 1024;                      // elements per head slot
  ushort* wT0 = (ushort*)(base + FEATS_BYTES);
  float*  bb0 = (float*)(base + FEATS_BYTES + 4 * WT_STRIDE_E * 2);
  (void)out_size; (void)ws_size; (void)n_in; (void)in_sizes;

  float* out = (float*)d_out;
  // output chunks (elements): scores @0, loc @4HW, ref @8HW, four @12HW
  float* outS = out;
  float* outL = out + (size_t)4  * HWSZ;
  float* outR = out + (size_t)8  * HWSZ;
  float* outF = out + (size_t)12 * HWSZ;

  // merged weight transform (grid.y = head: 0 score, 1 loc, 2 four, 3 ref)
  dim3 wxgrid(196, 4);
  wxform_all_kernel<<<wxgrid, 256, 0, stream>>>(
      (const float*)d_in[3],  (const float*)d_in[4],  (const float*)d_in[5],  (const float*)d_in[6],
      (const float*)d_in[9],  (const float*)d_in[10], (const float*)d_in[11], (const float*)d_in[12],
      (const float*)d_in[15], (const float*)d_in[16], (const float*)d_in[17], (const float*)d_in[18],
      (const float*)d_in[21], (const float*)d_in[22], (const float*)d_in[23], (const float*)d_in[24],
      wT0, bb0, WT_STRIDE_E);

  backbone_kernel<<<4608, 256, 0, stream>>>(input, bb_w, bb_b, feats);

  const ushort* wtS = wT0 + 0 * WT_STRIDE_E;
  const ushort* wtL = wT0 + 1 * WT_STRIDE_E;
  const ushort* wtF = wT0 + 2 * WT_STRIDE_E;
  const ushort* wtR = wT0 + 3 * WT_STRIDE_E;

  const int GRID = 2 * 48 * 48;                              // 4608

  // D1: loc (cout 2) + four (cout 20), both full 7x7
  heads2_kernel<false, 2, false, 20, false><<<GRID, 256, 0, stream>>>(
      feats, wtL, wtF, bb0 + 32, bb0 + 64,
      (const float*)d_in[13], (const float*)d_in[14],
      (const float*)d_in[19], (const float*)d_in[20],
      outL, outF);

  // D2: ref (cout 2, tanh) full 7x7 + score (cout 2) central-3x3-gated
  heads2_kernel<true, 2, true, 2, false><<<GRID, 256, 0, stream>>>(
      feats, wtR, wtS, bb0 + 96, bb0 + 0,
      (const float*)d_in[25], (const float*)d_in[26],
      (const float*)d_in[7],  (const float*)d_in[8],
      outR, outS);
}

// Round 9
// 414.872 us; speedup vs baseline: 2.0982x; 1.0850x over previous
//
#include <hip/hip_runtime.h>
#include <hip/hip_bf16.h>
#include <cmath>

#define HH 768
#define WW 768
#define HWSZ (768*768)

typedef __attribute__((ext_vector_type(8))) short bhalf8;   // 8 bf16 in 4 VGPRs
typedef __attribute__((ext_vector_type(4))) float f32x4;
typedef __attribute__((ext_vector_type(16))) float f32x16;

__device__ inline ushort f2bf(float f) {
  __hip_bfloat16 h = __float2bfloat16(f);
  return *reinterpret_cast<ushort*>(&h);
}

// ---------------- merged weight transform for all 4 heads ----------------
// grid.y = head index; w1[m][c][ky][kx] fp32 -> wT[pos][m][c] bf16 (s-folded); bb = b1*s + t
__global__ __launch_bounds__(256) void wxform_all_kernel(
    const float* __restrict__ w1S, const float* __restrict__ b1S,
    const float* __restrict__ sS,  const float* __restrict__ tS,
    const float* __restrict__ w1L, const float* __restrict__ b1L,
    const float* __restrict__ sL,  const float* __restrict__ tL,
    const float* __restrict__ w1F, const float* __restrict__ b1F,
    const float* __restrict__ sF,  const float* __restrict__ tF,
    const float* __restrict__ w1R, const float* __restrict__ b1R,
    const float* __restrict__ sR,  const float* __restrict__ tR,
    ushort* __restrict__ wT0, float* __restrict__ bb0, size_t wt_stride_elems)
{
  int h = blockIdx.y;
  const float *w1, *b1, *s, *t;
  int npos;
  if (h == 0)      { w1 = w1S; b1 = b1S; s = sS; t = tS; npos = 9;  }
  else if (h == 1) { w1 = w1L; b1 = b1L; s = sL; t = tL; npos = 49; }
  else if (h == 2) { w1 = w1F; b1 = b1F; s = sF; t = tF; npos = 49; }
  else             { w1 = w1R; b1 = b1R; s = sR; t = tR; npos = 49; }

  ushort* wT = wT0 + (size_t)h * wt_stride_elems;
  float*  bb = bb0 + h * 32;

  int i = blockIdx.x * 256 + threadIdx.x;
  if (i < npos * 1024) {
    int pos = i >> 10, mc = i & 1023, m = mc >> 5, c = mc & 31;
    wT[i] = f2bf(w1[(m * 32 + c) * npos + pos] * s[m]);
  }
  if (blockIdx.x == 0 && i < 32) bb[i] = b1[i] * s[i] + t[i];
}

// ---------------- backbone: conv3x3 (3->32) + bias + relu, feats[b][y][x][c] bf16 ----------------
__global__ __launch_bounds__(256) void backbone_kernel(
    const float* __restrict__ x, const float* __restrict__ w,
    const float* __restrict__ bias, ushort* __restrict__ feats)
{
  int p = blockIdx.x * 256 + threadIdx.x;          // 0 .. 2*HW-1
  int bb  = p / HWSZ;
  int rem = p - bb * HWSZ;
  int y   = rem / WW;
  int xx  = rem - y * WW;
  const float* xb = x + (size_t)bb * 3 * HWSZ;

  float v[3][3][3];
  #pragma unroll
  for (int c = 0; c < 3; c++)
    #pragma unroll
    for (int dy = 0; dy < 3; dy++)
      #pragma unroll
      for (int dx = 0; dx < 3; dx++) {
        int yy = y + dy - 1, xq = xx + dx - 1;
        v[c][dy][dx] = (yy >= 0 && yy < HH && xq >= 0 && xq < WW)
                         ? xb[(size_t)c * HWSZ + yy * WW + xq] : 0.f;
      }

  union { ushort u[32]; uint4 q[4]; } pk;
  #pragma unroll
  for (int o = 0; o < 32; o++) {
    float acc = bias[o];
    #pragma unroll
    for (int c = 0; c < 3; c++)
      #pragma unroll
      for (int dy = 0; dy < 3; dy++)
        #pragma unroll
        for (int dx = 0; dx < 3; dx++)
          acc = fmaf(w[((o * 3 + c) * 3 + dy) * 3 + dx], v[c][dy][dx], acc);
    pk.u[o] = f2bf(fmaxf(acc, 0.f));
  }
  uint4* dst = (uint4*)(feats + ((size_t)bb * HWSZ + rem) * 32);
  #pragma unroll
  for (int i = 0; i < 4; i++) dst[i] = pk.q[i];
}

// ---------------- per-head epilogue: BN+relu -> LDS -> 1x1 conv -> store ----------------
// mid: [256][36] f32
template <int COUT, bool DO_TANH>
__device__ inline void head_epilogue(
    const f32x16 acc[2], const float* __restrict__ bbh,
    const float* __restrict__ w2, const float* __restrict__ b2,
    float* __restrict__ out_base, float* mid,
    int wv, int qr, int qc, int kg, int by, int bx, int bb)
{
  #pragma unroll
  for (int n = 0; n < 2; n++) {
    int pix = (wv * 4 + 2 * n + qr) * 16 + qc;
    #pragma unroll
    for (int rg = 0; rg < 4; rg++) {
      int m0 = 8 * rg + 4 * kg;
      f32x4 v;
      #pragma unroll
      for (int j = 0; j < 4; j++)
        v[j] = fmaxf(acc[n][rg * 4 + j] + bbh[m0 + j], 0.f);
      *(f32x4*)(mid + pix * 36 + m0) = v;
    }
  }
  __syncthreads();

  int t = threadIdx.x;
  float mv[32];
  #pragma unroll
  for (int j2 = 0; j2 < 8; j2++)
    *(f32x4*)(mv + 4 * j2) = *(const f32x4*)(mid + t * 36 + 4 * j2);

  int oy = by * 16 + (t >> 4), ox = bx * 16 + (t & 15);
  size_t opix = (size_t)oy * WW + ox;
  float* ob = out_base + (size_t)bb * COUT * HWSZ;
  #pragma unroll
  for (int oc = 0; oc < COUT; oc++) {
    float a2 = b2[oc];
    #pragma unroll
    for (int m = 0; m < 32; m++) a2 = fmaf(w2[oc * 32 + m], mv[m], a2);
    if (DO_TANH) a2 = tanhf(a2) * 3.0f;
    ob[(size_t)oc * HWSZ + opix] = a2;
  }
  __syncthreads();   // before next head overwrites mid
}

// ---------------- heads3: loc + four (weights via LDS) + ref (weights via L1/L2) ----------------
// Pixel tile k-major: [row 22][g 4][col 22][8e]  -> elem off = row*704 + g*176 + col*8  (30976 B)
// Weight row buf:     [kx 7][h 2][g 4][m 32][8e] -> elem off = kx*2048 + h*1024 + g*256 + m*8 (28672 B)
// g = kh*2 + kg encodes the channel octet (c = kh*16 + kg*8 .. +8).
__global__ __launch_bounds__(256, 2) void heads3_kernel(
    const ushort* __restrict__ feats,
    const ushort* __restrict__ wtL, const ushort* __restrict__ wtF,
    const ushort* __restrict__ wtR,
    const float* __restrict__ bbL, const float* __restrict__ bbF,
    const float* __restrict__ bbR,
    const float* __restrict__ w2L, const float* __restrict__ b2L,
    const float* __restrict__ w2F, const float* __restrict__ b2F,
    const float* __restrict__ w2R, const float* __restrict__ b2R,
    float* __restrict__ outL, float* __restrict__ outF, float* __restrict__ outR)
{
  __shared__ __align__(16) char smem[30976 + 28672];     // 59648 B
  ushort* tile = (ushort*)smem;
  ushort* wrow = (ushort*)(smem + 30976);

  int bx = blockIdx.x % 48;
  int by = (blockIdx.x / 48) % 48;
  int bb = blockIdx.x / 2304;
  int x0 = bx * 16 - 3, y0 = by * 16 - 3;
  const ushort* fB = feats + (size_t)bb * HWSZ * 32;

  // ---- stage halo tile, k-major ----
  for (int p = threadIdx.x; p < 22 * 22; p += 256) {
    int r = p / 22, cl = p - r * 22;
    int yy = y0 + r, xx = x0 + cl;
    uint4 q0 = {0,0,0,0}, q1 = {0,0,0,0}, q2 = {0,0,0,0}, q3 = {0,0,0,0};
    if (yy >= 0 && yy < HH && xx >= 0 && xx < WW) {
      const uint4* src = (const uint4*)(fB + ((size_t)yy * WW + xx) * 32);
      q0 = src[0]; q1 = src[1]; q2 = src[2]; q3 = src[3];
    }
    ushort* dst = tile + r * 704 + cl * 8;
    *(uint4*)(dst +   0) = q0;     // g=0: c 0-7
    *(uint4*)(dst + 176) = q1;     // g=1: c 8-15
    *(uint4*)(dst + 352) = q2;     // g=2: c 16-23
    *(uint4*)(dst + 528) = q3;     // g=3: c 24-31
  }

  int l  = threadIdx.x & 63;
  int wv = threadIdx.x >> 6;                 // wave -> output rows wv*4..wv*4+3
  int q  = l & 31;                           // m row of A / pixel-in-group of B
  int kg = l >> 5;                           // k-octet subgroup
  int qr = q >> 4, qc = q & 15;

  const ushort* pbB = tile + (wv * 4 + qr) * 704 + kg * 176 + qc * 8;
  const ushort* aB  = wrow + kg * 256 + q * 8;
  const ushort* aRb = wtR + q * 32 + kg * 8;

  f32x16 accL[2] = {};
  f32x16 accF[2] = {};
  f32x16 accR[2] = {};

  #pragma unroll 1
  for (int ky = 0; ky < 7; ky++) {
    // ---- stage this ky-row of loc+four weights into LDS (k-major) ----
    // barrier also covers initial tile staging on ky==0 and protects wrow reuse
    {
      const ushort* rowL = wtL + ky * 7168;
      const ushort* rowF = wtF + ky * 7168;
      #pragma unroll
      for (int j = 0; j < 7; j++) {
        int c = j * 256 + (int)threadIdx.x;          // 0..1791
        int h = (c >= 896) ? 1 : 0;
        int o = (c - h * 896) * 8;                   // elem in [0,7168)
        bhalf8 v = *(const bhalf8*)((h ? rowF : rowL) + o);
        int tap = o >> 10, rem = o & 1023;
        *(bhalf8*)(wrow + tap * 2048 + h * 1024 + ((rem >> 3) & 3) * 256 + (rem >> 5) * 8) = v;
      }
    }
    __syncthreads();

    const ushort* pbrow = pbB + ky * 704;
    const ushort* aR = aRb + ky * 7168;

    #pragma unroll
    for (int kx = 0; kx < 7; kx++) {
      bhalf8 fL[2], fF[2], fR[2];
      #pragma unroll
      for (int kh = 0; kh < 2; kh++) {
        fL[kh] = *(const bhalf8*)(aB + kx * 2048 +        kh * 512);
        fF[kh] = *(const bhalf8*)(aB + kx * 2048 + 1024 + kh * 512);
        fR[kh] = *(const bhalf8*)(aR + kx * 1024 + kh * 16);
      }
      bhalf8 bfr[2][2];
      #pragma unroll
      for (int n = 0; n < 2; n++)
        #pragma unroll
        for (int kh = 0; kh < 2; kh++)
          bfr[n][kh] = *(const bhalf8*)(pbrow + n * 1408 + kh * 352 + kx * 8);

      #pragma unroll
      for (int n = 0; n < 2; n++)
        #pragma unroll
        for (int kh = 0; kh < 2; kh++) {
          accL[n] = __builtin_amdgcn_mfma_f32_32x32x16_bf16(fL[kh], bfr[n][kh], accL[n], 0, 0, 0);
          accF[n] = __builtin_amdgcn_mfma_f32_32x32x16_bf16(fF[kh], bfr[n][kh], accF[n], 0, 0, 0);
          accR[n] = __builtin_amdgcn_mfma_f32_32x32x16_bf16(fR[kh], bfr[n][kh], accR[n], 0, 0, 0);
        }
    }
    __syncthreads();   // all reads of wrow done before next stage
  }

  float* mid = (float*)smem;

  head_epilogue<2,  false>(accL, bbL, w2L, b2L, outL, mid, wv, qr, qc, kg, by, bx, bb);
  head_epilogue<20, false>(accF, bbF, w2F, b2F, outF, mid, wv, qr, qc, kg, by, bx, bb);
  head_epilogue<2,  true >(accR, bbR, w2R, b2R, outR, mid, wv, qr, qc, kg, by, bx, bb);
}

// ---------------- score: single head, 3x3, high occupancy ----------------
__global__ __launch_bounds__(256, 4) void score_kernel(
    const ushort* __restrict__ feats,
    const ushort* __restrict__ wtS, const float* __restrict__ bbS,
    const float* __restrict__ w2S, const float* __restrict__ b2S,
    float* __restrict__ outS)
{
  constexpr int TW = 18, CPAD = 40;                // 18x18 halo tile
  constexpr int SMEM_BYTES = 256 * 36 * 4;         // 36864 >= 18*18*80=25920
  __shared__ __align__(16) char smem[SMEM_BYTES];
  ushort* tile = (ushort*)smem;

  int bx = blockIdx.x % 48;
  int by = (blockIdx.x / 48) % 48;
  int bb = blockIdx.x / 2304;
  int x0 = bx * 16 - 1, y0 = by * 16 - 1;
  const ushort* fB = feats + (size_t)bb * HWSZ * 32;

  for (int p = threadIdx.x; p < TW * TW; p += 256) {
    int py = p / TW, pxx = p % TW;
    int yy = y0 + py, xx = x0 + pxx;
    uint4 q0 = {0,0,0,0}, q1 = {0,0,0,0}, q2 = {0,0,0,0}, q3 = {0,0,0,0};
    if (yy >= 0 && yy < HH && xx >= 0 && xx < WW) {
      const uint4* src = (const uint4*)(fB + ((size_t)yy * WW + xx) * 32);
      q0 = src[0]; q1 = src[1]; q2 = src[2]; q3 = src[3];
    }
    uint4* dst = (uint4*)(tile + (size_t)p * CPAD);
    dst[0] = q0; dst[1] = q1; dst[2] = q2; dst[3] = q3;
  }
  __syncthreads();

  int l  = threadIdx.x & 63;
  int wv = threadIdx.x >> 6;
  int q  = l & 31;
  int kg = l >> 5;
  int qr = q >> 4, qc = q & 15;

  const ushort* pb = tile + ((wv * 4 + qr) * TW + qc) * CPAD + kg * 8;
  const int aoff = q * 32 + kg * 8;

  f32x16 acc[2] = {};

  #pragma unroll
  for (int ky = 0; ky < 3; ky++) {
    #pragma unroll
    for (int kx = 0; kx < 3; kx++) {
      const int tap = ky * 3 + kx;
      bhalf8 a0[2];
      #pragma unroll
      for (int kh = 0; kh < 2; kh++)
        a0[kh] = *(const bhalf8*)(wtS + tap * 1024 + aoff + kh * 16);
      #pragma unroll
      for (int n = 0; n < 2; n++) {
        #pragma unroll
        for (int kh = 0; kh < 2; kh++) {
          bhalf8 bf = *(const bhalf8*)(pb + (ky * TW + kx) * CPAD
                                          + n * 2 * TW * CPAD + kh * 16);
          acc[n] = __builtin_amdgcn_mfma_f32_32x32x16_bf16(a0[kh], bf, acc[n], 0, 0, 0);
        }
      }
    }
  }

  __syncthreads();
  float* mid = (float*)smem;
  head_epilogue<2, false>(acc, bbS, w2S, b2S, outS, mid, wv, qr, qc, kg, by, bx, bb);
}

extern "C" void kernel_launch(void* const* d_in, const int* in_sizes, int n_in,
                              void* d_out, int out_size, void* d_ws, size_t ws_size,
                              hipStream_t stream) {
  const float* input = (const float*)d_in[0];
  const float* bb_w  = (const float*)d_in[1];
  const float* bb_b  = (const float*)d_in[2];

  ushort* feats = (ushort*)d_ws;                             // 2*HW*32 bf16 = 75.5 MB
  char* base = (char*)d_ws;
  const size_t FEATS_BYTES = (size_t)2 * HWSZ * 32 * 2;
  const size_t WT_STRIDE_E = 49 * 1024;                      // elements per head slot
  ushort* wT0 = (ushort*)(base + FEATS_BYTES);
  float*  bb0 = (float*)(base + FEATS_BYTES + 4 * WT_STRIDE_E * 2);
  (void)out_size; (void)ws_size; (void)n_in; (void)in_sizes;

  float* out = (float*)d_out;
  // output chunks (elements): scores @0, loc @4HW, ref @8HW, four @12HW
  float* outS = out;
  float* outL = out + (size_t)4  * HWSZ;
  float* outR = out + (size_t)8  * HWSZ;
  float* outF = out + (size_t)12 * HWSZ;

  // merged weight transform (grid.y = head: 0 score, 1 loc, 2 four, 3 ref)
  dim3 wxgrid(196, 4);
  wxform_all_kernel<<<wxgrid, 256, 0, stream>>>(
      (const float*)d_in[3],  (const float*)d_in[4],  (const float*)d_in[5],  (const float*)d_in[6],
      (const float*)d_in[9],  (const float*)d_in[10], (const float*)d_in[11], (const float*)d_in[12],
      (const float*)d_in[15], (const float*)d_in[16], (const float*)d_in[17], (const float*)d_in[18],
      (const float*)d_in[21], (const float*)d_in[22], (const float*)d_in[23], (const float*)d_in[24],
      wT0, bb0, WT_STRIDE_E);

  backbone_kernel<<<4608, 256, 0, stream>>>(input, bb_w, bb_b, feats);

  const ushort* wtS = wT0 + 0 * WT_STRIDE_E;
  const ushort* wtL = wT0 + 1 * WT_STRIDE_E;
  const ushort* wtF = wT0 + 2 * WT_STRIDE_E;
  const ushort* wtR = wT0 + 3 * WT_STRIDE_E;

  const int GRID = 2 * 48 * 48;                              // 4608

  heads3_kernel<<<GRID, 256, 0, stream>>>(
      feats, wtL, wtF, wtR,
      bb0 + 32, bb0 + 64, bb0 + 96,
      (const float*)d_in[13], (const float*)d_in[14],
      (const float*)d_in[19], (const float*)d_in[20],
      (const float*)d_in[25], (const float*)d_in[26],
      outL, outF, outR);

  score_kernel<<<GRID, 256, 0, stream>>>(
      feats, wtS, bb0 + 0,
      (const float*)d_in[7], (const float*)d_in[8], outS);
}